// Round 17
// baseline (24.845 us; speedup 1.0000x reference)
//
#include <hip/hip_runtime.h>

#define BB 2
#define NN 1024
#define FF 128
#define H1 64
#define H2 32
#define XPAD 136  // x-row stride in f16 (128+8)
#define PAD 72    // p-row stride in f16 (64+8)

typedef __attribute__((ext_vector_type(4))) _Float16 half4;   // 4 f16 (8B)
typedef __attribute__((ext_vector_type(8))) _Float16 half8;   // 8 f16 (4 VGPR)
typedef __attribute__((ext_vector_type(16))) float f32x16;    // 32x32 MFMA acc
typedef __attribute__((ext_vector_type(2))) float f32x2;      // v_pk_*_f32

// e = relu(a + b) in packed f16: 4x v_pk_add_f16 + 4x v_pk_max_f16
__device__ inline half8 addrelu8(half8 a, half8 b) {
    half8 s = a + b;
    const half8 z = {};
    return __builtin_elementwise_max(s, z);
}

// ---------------------------------------------------------------------------
// ZERO-SYNC full fusion, v8: j-consolidated phase B.
// R16 reverted (hoist+swizzle +0.7). New model term: phase B's row reads are
// uniform-address b128 BROADCASTS — 4KB delivered per step for 128B unique
// (both jhalf-waves re-read the same rows; every lane receives the full
// slice). At ~12cy/ds_read_b128 that is ~5.1us of per-CU LDS-pipe time =
// 44% of phase B's 11.7us. v8: each wave owns 8 i-rows x ALL 64 j-cols:
//   one row read -> two E-builds (qjA: j 0-31, qjB: j 32-63) -> two
//   INDEPENDENT 4-MFMA chains -> 64 outputs.
// LDS read traffic halves; 2x MFMA ILP (chains independent — replaces the
// R11 pipeline, which was null); iterations halve; store = one full-wave
// 256B line per step. VALU/output unchanged. ~140 VGPR -> (512,2).
// Per-output arithmetic bit-identical -> absmax unchanged.
// Pre-commit: null kills the LDS-BW theory -> R18 instruments phase A.
// ---------------------------------------------------------------------------
__global__ __launch_bounds__(512, 2) void fused_kernel(
    const float* __restrict__ x, const float* __restrict__ W1,
    const float* __restrict__ b1, const float* __restrict__ W2,
    const float* __restrict__ b2, const float* __restrict__ W3,
    const float* __restrict__ b3, float* __restrict__ out)
{
    __shared__ __align__(16) _Float16 xlds[128][XPAD];  // 34.8 KB staged x
    __shared__ __align__(16) _Float16 plds[64][PAD];    // 9.2 KB pib rows
    __shared__ __align__(16) _Float16 pjlds[64][PAD];   // 9.2 KB pj rows

    const int tid  = threadIdx.x;
    const int lane = tid & 63;
    const int wv   = tid >> 6;                // 0..7
    const int bid  = blockIdx.x;

    const int b   = bid >> 8;                 // 256 blocks per batch
    const int rem = bid & 255;
    const int i0  = (rem >> 4) * 64;          // 16 i-tiles (64 rows each)
    const int j0  = (rem & 15) * 64;          // 16 j-tiles (64 cols each)
    const int jn  = lane & 31;                // m/n lane index
    const int hi  = lane >> 5;                // k-group half
    const int m   = jn;

    // ============ stage: 128 x-rows -> xlds (coalesced, f16) ==============
    // rows 0..63 = i-rows i0..i0+63; rows 64..127 = j-rows j0..j0+63.
    {
        const int xb_i = b * NN + i0, xb_j = b * NN + j0 - 64;
        #pragma unroll
        for (int it = 0; it < 8; ++it) {
            const int idx = tid + it * 512;
            const int row = idx >> 5, c4 = (idx & 31) * 4;
            const int gr  = (row < 64 ? xb_i : xb_j) + row;
            const float4 v = *(const float4*)(x + (size_t)gr * FF + c4);
            half4 hv = {(_Float16)v.x, (_Float16)v.y,
                        (_Float16)v.z, (_Float16)v.w};
            *(half4*)&xlds[row][c4] = hv;
        }
    }
    __syncthreads();

    // ============ phase A: 8 gemm units, ONE per wave (balanced) ==========
    //   wv0/1: pib rows  0-31 (htile 0/1)   wv2/3: pib rows 32-63
    //   wv4/5: pj  rows  0-31               wv6/7: pj  rows 32-63
    {
        const int xrow0 = ((wv & 2) ? 32 : 0) + ((wv & 4) ? 64 : 0);
        const int htile = wv & 1;
        const int koff  = (wv & 4) ? 0 : FF;
        _Float16* dstbase = (wv & 4) ? &pjlds[xrow0 - 64][0] : &plds[xrow0][0];
        const float* bias = (wv & 4) ? nullptr : b1;

        f32x16 acc = {};
        #pragma unroll
        for (int ks = 0; ks < 8; ++ks) {
            const int k0 = ks * 16 + hi * 8;
            half8 af;
            const float* wb = W1 + (size_t)(koff + k0) * H1 + htile * 32 + m;
            #pragma unroll
            for (int e = 0; e < 8; ++e)
                af[e] = (_Float16)wb[(size_t)e * H1];     // coalesced per e
            const half8 bf = *(const half8*)&xlds[xrow0 + m][k0];
            acc = __builtin_amdgcn_mfma_f32_32x32x16_f16(af, bf, acc, 0, 0, 0);
        }
        _Float16* drow = dstbase + (size_t)m * PAD;       // D col -> LDS row
        #pragma unroll
        for (int q = 0; q < 4; ++q) {                     // packed b64 stores
            half4 hv;
            #pragma unroll
            for (int jj = 0; jj < 4; ++jj) {
                const int r  = q * 4 + jj;                // hl=(r&3)+8(r>>2)+4hi
                const int hg = htile * 32 + 8 * q + 4 * hi + jj;
                float v = acc[r];
                if (bias) v += bias[hg];
                hv[jj] = (_Float16)v;
            }
            *(half4*)(drow + htile * 32 + 8 * q + 4 * hi) = hv;
        }
    }

    // ============ per-wave edge init (weights straight from global) =======
    half8 wa[4];
    #pragma unroll
    for (int c4 = 0; c4 < 4; ++c4)
        #pragma unroll
        for (int e = 0; e < 8; ++e)
            wa[c4][e] = (_Float16)W2[(16 * c4 + hi * 8 + e) * H2 + jn];

    f32x16 ci;
    #pragma unroll
    for (int r = 0; r < 16; ++r) {           // D row mapping [m74/m101]
        const int row = (r & 3) + 8 * (r >> 2) + 4 * hi;
        ci[r] = b2[row];
    }
    // W3 paired for the packed epilogue (R10 layout, verified)
    f32x2 w32[8];
    #pragma unroll
    for (int q = 0; q < 8; ++q) {
        const int row = ((2 * q) & 3) + 8 * (q >> 1) + 4 * hi;
        w32[q] = (f32x2){W3[row], W3[row + 1]};
    }
    const float b3v = b3[0];

    __syncthreads();   // phase A LDS writes visible to all waves

    // B-frags for BOTH j-halves: qjA = pj rows 0-31 (col jn), qjB = rows 32-63
    const _Float16* prA = &pjlds[jn][hi * 8];
    const _Float16* prB = &pjlds[32 + jn][hi * 8];
    const half8 qjA0 = *(const half8*)(prA);
    const half8 qjA1 = *(const half8*)(prA + 16);
    const half8 qjA2 = *(const half8*)(prA + 32);
    const half8 qjA3 = *(const half8*)(prA + 48);
    const half8 qjB0 = *(const half8*)(prB);
    const half8 qjB1 = *(const half8*)(prB + 16);
    const half8 qjB2 = *(const half8*)(prB + 32);
    const half8 qjB3 = *(const half8*)(prB + 48);

    // R10 packed epilogue (incl. cross-half shfl)
    auto epi = [&](const f32x16& dd) -> float {
        const f32x2 z2 = {0.f, 0.f};
        f32x2 s[4] = {z2, z2, z2, z2};
        #pragma unroll
        for (int q = 0; q < 8; ++q) {
            f32x2 dp = {dd[2 * q], dd[2 * q + 1]};
            dp = __builtin_elementwise_max(dp, z2);
            s[q & 3] = __builtin_elementwise_fma(dp, w32[q], s[q & 3]);
        }
        const f32x2 t01 = s[0] + s[1];
        const f32x2 t23 = s[2] + s[3];
        const f32x2 tt  = t01 + t23;
        float p = tt[0] + tt[1];
        p += __shfl_xor(p, 32);   // lane-halves hold complementary rows
        return p;
    };

    // ============ phase B: 8 steps, 1 i-row x 64 j-cols each ==============
    const _Float16* irbase = &plds[wv * 8][hi * 8];
    float* obase = out + (size_t)(b * NN + i0 + wv * 8) * NN
                       + j0 + hi * 32 + jn;

    #pragma unroll 1
    for (int t = 0; t < 8; ++t) {
        // ONE row read (4 uniform b128) feeds both j-halves
        const _Float16* ir = irbase + t * PAD;
        const half8 r0 = *(const half8*)(ir);
        const half8 r1 = *(const half8*)(ir + 16);
        const half8 r2 = *(const half8*)(ir + 32);
        const half8 r3 = *(const half8*)(ir + 48);
        // E-builds for both halves (row dies here)
        const half8 a0 = addrelu8(qjA0, r0);
        const half8 a1 = addrelu8(qjA1, r1);
        const half8 a2 = addrelu8(qjA2, r2);
        const half8 a3 = addrelu8(qjA3, r3);
        const half8 g0 = addrelu8(qjB0, r0);
        const half8 g1 = addrelu8(qjB1, r1);
        const half8 g2 = addrelu8(qjB2, r2);
        const half8 g3 = addrelu8(qjB3, r3);
        // two INDEPENDENT 4-MFMA chains (2x matrix-pipe ILP)
        f32x16 dA, dB;
        dA = __builtin_amdgcn_mfma_f32_32x32x16_f16(wa[0], a0, ci, 0, 0, 0);
        dB = __builtin_amdgcn_mfma_f32_32x32x16_f16(wa[0], g0, ci, 0, 0, 0);
        dA = __builtin_amdgcn_mfma_f32_32x32x16_f16(wa[1], a1, dA, 0, 0, 0);
        dB = __builtin_amdgcn_mfma_f32_32x32x16_f16(wa[1], g1, dB, 0, 0, 0);
        dA = __builtin_amdgcn_mfma_f32_32x32x16_f16(wa[2], a2, dA, 0, 0, 0);
        dB = __builtin_amdgcn_mfma_f32_32x32x16_f16(wa[2], g2, dB, 0, 0, 0);
        dA = __builtin_amdgcn_mfma_f32_32x32x16_f16(wa[3], a3, dA, 0, 0, 0);
        dB = __builtin_amdgcn_mfma_f32_32x32x16_f16(wa[3], g3, dB, 0, 0, 0);
        // epilogues; hi=0 half stores the A-col, hi=1 the B-col -> one
        // contiguous 256B full-wave store per step
        const float pA = epi(dA);
        const float pB = epi(dB);
        obase[(size_t)t * NN] = (hi ? pB : pA) + b3v;
    }
}

extern "C" void kernel_launch(void* const* d_in, const int* in_sizes, int n_in,
                              void* d_out, int out_size, void* d_ws, size_t ws_size,
                              hipStream_t stream) {
    const float* x  = (const float*)d_in[0];
    // d_in[1] = adj (UNUSED by reference), d_in[2] = mask (UNUSED)
    const float* W1 = (const float*)d_in[3];
    const float* b1 = (const float*)d_in[4];
    const float* W2 = (const float*)d_in[5];
    const float* b2 = (const float*)d_in[6];
    const float* W3 = (const float*)d_in[7];
    const float* b3 = (const float*)d_in[8];
    float* out = (float*)d_out;

    // single self-sufficient launch; 512 blocks x 512 threads
    fused_kernel<<<BB * NN * NN / (64 * 64), 512, 0, stream>>>(
        x, W1, b1, W2, b2, W3, b3, out);
}